// Round 1
// baseline (1077.731 us; speedup 1.0000x reference)
//
#include <hip/hip_runtime.h>
#include <math.h>

constexpr int Bc = 4, Tc = 24, Cc = 128, Hc = 48, Wc = 48;
constexpr int HWp = Hc * Wc;            // 2304
constexpr int NHEAD = 16, DKc = 4, DM = 128;
constexpr float EPS = 1e-5f;

__global__ __launch_bounds__(256) void ltae_fused(
    const float* __restrict__ x, const int* __restrict__ bpos,
    const float* __restrict__ w_in0, const float* __restrict__ b_in0,
    const float* __restrict__ g_in0, const float* __restrict__ be_in0,
    const float* __restrict__ w_in1, const float* __restrict__ b_in1,
    const float* __restrict__ g_in1, const float* __restrict__ be_in1,
    const float* __restrict__ g_innorm, const float* __restrict__ b_innorm,
    const float* __restrict__ Qm, const float* __restrict__ w_k,
    const float* __restrict__ b_k,
    const float* __restrict__ w_m0, const float* __restrict__ b_m0,
    const float* __restrict__ g_m0, const float* __restrict__ be_m0,
    const float* __restrict__ w_m1, const float* __restrict__ b_m1,
    const float* __restrict__ g_m1, const float* __restrict__ be_m1,
    const float* __restrict__ g_out, const float* __restrict__ b_out,
    float* __restrict__ out)
{
    __shared__ float xs[Tc][Cc];      // tokens -> later h2 -> later "out" (post norm+pe)
    __shared__ float h1[Tc][256];
    __shared__ float qk[NHEAD][Cc];
    __shared__ float pe_s[Tc][8];
    __shared__ float sc[NHEAD][Tc];
    __shared__ float mu_s[16], rs_s[16];
    __shared__ float qb_s[NHEAD];
    __shared__ float ovec[DM];
    __shared__ float mm0[256];

    const int n   = blockIdx.x;
    const int b   = n / HWp;
    const int pix = n - b * HWp;
    const int tid = threadIdx.x;

    // ---- Phase 0: gather token matrix + PE table ----
    for (int i = tid; i < Tc * Cc; i += 256) {
        int t = i >> 7, c = i & 127;
        xs[t][c] = x[((size_t)((b * Tc + t) * Cc + c)) * HWp + pix];
    }
    if (tid < Tc * 8) {
        int t = tid >> 3, d = tid & 7;
        const float dens[4] = {1.0f, 5.623413251903491f, 31.622776601683793f, 177.82794100389228f};
        float pos = (float)bpos[b * Tc + t];
        float ang = pos / dens[d >> 1];
        pe_s[t][d] = (d & 1) ? cosf(ang) : sinf(ang);
    }
    __syncthreads();

    // ---- Phase 1: linear1 (128->256) + GN(4 over 64) + ReLU -> h1 ----
    {
        const int o = tid;
        float acc[Tc];
        #pragma unroll
        for (int t = 0; t < Tc; t++) acc[t] = 0.f;
        const float* wr = w_in0 + o * Cc;
        #pragma unroll
        for (int c0 = 0; c0 < Cc; c0 += 32) {
            float wv[32];
            #pragma unroll
            for (int j = 0; j < 32; j += 4) {
                float4 v = *(const float4*)(wr + c0 + j);
                wv[j] = v.x; wv[j+1] = v.y; wv[j+2] = v.z; wv[j+3] = v.w;
            }
            #pragma unroll
            for (int t = 0; t < Tc; t++) {
                #pragma unroll
                for (int j = 0; j < 32; j += 4) {
                    float4 xv = *(const float4*)(&xs[t][c0 + j]);
                    acc[t] = fmaf(xv.x, wv[j],   acc[t]);
                    acc[t] = fmaf(xv.y, wv[j+1], acc[t]);
                    acc[t] = fmaf(xv.z, wv[j+2], acc[t]);
                    acc[t] = fmaf(xv.w, wv[j+3], acc[t]);
                }
            }
        }
        const float bias = b_in0[o], gg = g_in0[o], bb = be_in0[o];
        #pragma unroll
        for (int t = 0; t < Tc; t++) {
            float v = acc[t] + bias;
            float s = v, s2 = v * v;
            #pragma unroll
            for (int m = 1; m <= 32; m <<= 1) { s += __shfl_xor(s, m); s2 += __shfl_xor(s2, m); }
            float mu  = s  * (1.f / 64.f);
            float var = s2 * (1.f / 64.f) - mu * mu;
            float xn  = (v - mu) * rsqrtf(var + EPS);
            float hv  = fmaf(xn, gg, bb);
            h1[t][o] = fmaxf(hv, 0.f);
        }
    }
    __syncthreads();

    // ---- Phase 2: linear2 (256->128) + GN(4 over 32) + ReLU -> xs (h2) ----
    {
        const int o = tid & 127;
        const int half = tid >> 7;          // 12 tokens each
        float acc[12];
        #pragma unroll
        for (int q = 0; q < 12; q++) acc[q] = 0.f;
        const float* wr = w_in1 + o * 256;
        #pragma unroll
        for (int c0 = 0; c0 < 256; c0 += 32) {
            float wv[32];
            #pragma unroll
            for (int j = 0; j < 32; j += 4) {
                float4 v = *(const float4*)(wr + c0 + j);
                wv[j] = v.x; wv[j+1] = v.y; wv[j+2] = v.z; wv[j+3] = v.w;
            }
            #pragma unroll
            for (int q = 0; q < 12; q++) {
                const int t = half * 12 + q;
                #pragma unroll
                for (int j = 0; j < 32; j += 4) {
                    float4 xv = *(const float4*)(&h1[t][c0 + j]);
                    acc[q] = fmaf(xv.x, wv[j],   acc[q]);
                    acc[q] = fmaf(xv.y, wv[j+1], acc[q]);
                    acc[q] = fmaf(xv.z, wv[j+2], acc[q]);
                    acc[q] = fmaf(xv.w, wv[j+3], acc[q]);
                }
            }
        }
        const float bias = b_in1[o], gg = g_in1[o], bb = be_in1[o];
        #pragma unroll
        for (int q = 0; q < 12; q++) {
            const int t = half * 12 + q;
            float v = acc[q] + bias;
            float s = v, s2 = v * v;
            #pragma unroll
            for (int m = 1; m <= 16; m <<= 1) { s += __shfl_xor(s, m); s2 += __shfl_xor(s2, m); }
            float mu  = s  * (1.f / 32.f);
            float var = s2 * (1.f / 32.f) - mu * mu;
            float xn  = (v - mu) * rsqrtf(var + EPS);
            float hv  = fmaf(xn, gg, bb);
            xs[t][o] = fmaxf(hv, 0.f);
        }
    }
    __syncthreads();

    // ---- Phase 3: in_norm GN(16 over C,T) + positional encoding ----
    {
        const int g = tid >> 4, j = tid & 15;   // 16 threads per group
        float s = 0.f, s2 = 0.f;
        #pragma unroll
        for (int k = 0; k < 12; k++) {
            int e = j + 16 * k;                 // 0..191
            int t = e >> 3, co = e & 7;
            float v = xs[t][g * 8 + co];
            s += v; s2 += v * v;
        }
        #pragma unroll
        for (int m = 1; m <= 8; m <<= 1) { s += __shfl_xor(s, m); s2 += __shfl_xor(s2, m); }
        if (j == 0) {
            float mu  = s  * (1.f / 192.f);
            float var = s2 * (1.f / 192.f) - mu * mu;
            mu_s[g] = mu; rs_s[g] = rsqrtf(var + EPS);
        }
    }
    __syncthreads();
    for (int i = tid; i < Tc * Cc; i += 256) {
        int t = i >> 7, c = i & 127, g = c >> 3;
        float v = (xs[t][c] - mu_s[g]) * rs_s[g] * g_innorm[c] + b_innorm[c] + pe_s[t][c & 7];
        xs[t][c] = v;
    }
    __syncthreads();

    // ---- Phase 4: attention ----
    for (int i = tid; i < NHEAD * Cc; i += 256) {
        int h = i >> 7, c = i & 127;
        float s = 0.f;
        #pragma unroll
        for (int dk = 0; dk < DKc; dk++)
            s = fmaf(Qm[h * DKc + dk], w_k[(h * DKc + dk) * Cc + c], s);
        qk[h][c] = s;
    }
    if (tid < NHEAD) {
        float s = 0.f;
        #pragma unroll
        for (int dk = 0; dk < DKc; dk++) s = fmaf(Qm[tid * DKc + dk], b_k[tid * DKc + dk], s);
        qb_s[tid] = s;
    }
    __syncthreads();
    for (int i = tid; i < NHEAD * Tc; i += 256) {
        int h = i / Tc, t = i - h * Tc;
        float s = qb_s[h];
        #pragma unroll
        for (int c = 0; c < Cc; c += 4) {
            float4 a4 = *(const float4*)(&xs[t][c]);
            float4 q4 = *(const float4*)(&qk[h][c]);
            s = fmaf(a4.x, q4.x, s); s = fmaf(a4.y, q4.y, s);
            s = fmaf(a4.z, q4.z, s); s = fmaf(a4.w, q4.w, s);
        }
        sc[h][t] = 0.5f * s;
    }
    __syncthreads();
    if (tid < NHEAD) {
        float mx = -1e30f;
        #pragma unroll
        for (int t = 0; t < Tc; t++) mx = fmaxf(mx, sc[tid][t]);
        float sum = 0.f;
        #pragma unroll
        for (int t = 0; t < Tc; t++) { float e = expf(sc[tid][t] - mx); sum += e; sc[tid][t] = e; }
        float inv = 1.f / sum;
        #pragma unroll
        for (int t = 0; t < Tc; t++) sc[tid][t] *= inv;
    }
    __syncthreads();
    if (tid < DM) {
        int h = tid >> 3, vv = tid & 7;
        float s = 0.f;
        #pragma unroll
        for (int t = 0; t < Tc; t++) s = fmaf(sc[h][t], xs[t][h * 8 + vv], s);
        ovec[tid] = s;
    }
    __syncthreads();

    // ---- Phase 5: output MLP + out_norm + store ----
    {
        const int o = tid;
        float s = b_m0[o];
        const float* wr = w_m0 + o * Cc;
        #pragma unroll
        for (int c = 0; c < Cc; c += 4) {
            float4 w4 = *(const float4*)(wr + c);
            float4 x4 = *(const float4*)(&ovec[c]);
            s = fmaf(w4.x, x4.x, s); s = fmaf(w4.y, x4.y, s);
            s = fmaf(w4.z, x4.z, s); s = fmaf(w4.w, x4.w, s);
        }
        float sr = s, s2 = s * s;
        #pragma unroll
        for (int m = 1; m <= 32; m <<= 1) { sr += __shfl_xor(sr, m); s2 += __shfl_xor(s2, m); }
        float mu  = sr * (1.f / 64.f);
        float var = s2 * (1.f / 64.f) - mu * mu;
        float xn  = (s - mu) * rsqrtf(var + EPS);
        float hv  = fmaf(xn, g_m0[o], be_m0[o]);
        mm0[o] = fmaxf(hv, 0.f);
    }
    __syncthreads();
    if (tid < DM) {
        const int o = tid;
        float s = b_m1[o];
        const float* wr = w_m1 + o * 256;
        #pragma unroll
        for (int c = 0; c < 256; c += 4) {
            float4 w4 = *(const float4*)(wr + c);
            float4 x4 = *(const float4*)(&mm0[c]);
            s = fmaf(w4.x, x4.x, s); s = fmaf(w4.y, x4.y, s);
            s = fmaf(w4.z, x4.z, s); s = fmaf(w4.w, x4.w, s);
        }
        // GN(4 over 32)
        float sr = s, s2 = s * s;
        #pragma unroll
        for (int m = 1; m <= 16; m <<= 1) { sr += __shfl_xor(sr, m); s2 += __shfl_xor(s2, m); }
        float mu  = sr * (1.f / 32.f);
        float var = s2 * (1.f / 32.f) - mu * mu;
        float xn  = (s - mu) * rsqrtf(var + EPS);
        float v2  = fmaxf(fmaf(xn, g_m1[o], be_m1[o]), 0.f);
        // out_norm GN(16 over 8)
        float t1 = v2, t2 = v2 * v2;
        #pragma unroll
        for (int m = 1; m <= 4; m <<= 1) { t1 += __shfl_xor(t1, m); t2 += __shfl_xor(t2, m); }
        float mu2  = t1 * (1.f / 8.f);
        float var2 = t2 * (1.f / 8.f) - mu2 * mu2;
        float xn2  = (v2 - mu2) * rsqrtf(var2 + EPS);
        float y = fmaf(xn2, g_out[o], b_out[o]);
        out[((size_t)(b * Cc + o)) * HWp + pix] = y;
    }
}

extern "C" void kernel_launch(void* const* d_in, const int* in_sizes, int n_in,
                              void* d_out, int out_size, void* d_ws, size_t ws_size,
                              hipStream_t stream) {
    const float* x        = (const float*)d_in[0];
    const int*   bpos     = (const int*)  d_in[1];
    const float* w_in0    = (const float*)d_in[2];
    const float* b_in0    = (const float*)d_in[3];
    const float* g_in0    = (const float*)d_in[4];
    const float* be_in0   = (const float*)d_in[5];
    const float* w_in1    = (const float*)d_in[6];
    const float* b_in1    = (const float*)d_in[7];
    const float* g_in1    = (const float*)d_in[8];
    const float* be_in1   = (const float*)d_in[9];
    const float* g_innorm = (const float*)d_in[10];
    const float* b_innorm = (const float*)d_in[11];
    const float* Qm       = (const float*)d_in[12];
    const float* w_k      = (const float*)d_in[13];
    const float* b_k      = (const float*)d_in[14];
    const float* w_m0     = (const float*)d_in[15];
    const float* b_m0     = (const float*)d_in[16];
    const float* g_m0     = (const float*)d_in[17];
    const float* be_m0    = (const float*)d_in[18];
    const float* w_m1     = (const float*)d_in[19];
    const float* b_m1     = (const float*)d_in[20];
    const float* g_m1     = (const float*)d_in[21];
    const float* be_m1    = (const float*)d_in[22];
    const float* g_out    = (const float*)d_in[23];
    const float* b_out    = (const float*)d_in[24];

    hipLaunchKernelGGL(ltae_fused, dim3(Bc * HWp), dim3(256), 0, stream,
                       x, bpos, w_in0, b_in0, g_in0, be_in0, w_in1, b_in1, g_in1, be_in1,
                       g_innorm, b_innorm, Qm, w_k, b_k,
                       w_m0, b_m0, g_m0, be_m0, w_m1, b_m1, g_m1, be_m1, g_out, b_out,
                       (float*)d_out);
}

// Round 3
// 483.671 us; speedup vs baseline: 2.2282x; 2.2282x over previous
//
#include <hip/hip_runtime.h>
#include <math.h>

typedef _Float16 f16x8 __attribute__((ext_vector_type(8)));
typedef float f32x4 __attribute__((ext_vector_type(4)));

constexpr int HWp = 2304;
constexpr float EPS = 1e-5f;

// ---------------- prep: weights -> split fp16 (hi/lo), fold Q into w_k ----------------
__global__ void ltae_prep(const float* __restrict__ w_in0, const float* __restrict__ w_in1,
                          const float* __restrict__ Qm, const float* __restrict__ w_k,
                          const float* __restrict__ b_k,
                          _Float16* __restrict__ w1h, _Float16* __restrict__ w1l,
                          _Float16* __restrict__ w2h, _Float16* __restrict__ w2l,
                          float* __restrict__ qkG, float* __restrict__ qbG) {
    int i = blockIdx.x * 256 + threadIdx.x;
    if (i < 32768) {
        float v = w_in0[i];
        _Float16 h = (_Float16)v;
        w1h[i] = h; w1l[i] = (_Float16)(v - (float)h);
    } else if (i < 65536) {
        int j = i - 32768;
        float v = w_in1[j];
        _Float16 h = (_Float16)v;
        w2h[j] = h; w2l[j] = (_Float16)(v - (float)h);
    } else if (i < 67584) {
        int j = i - 65536; int h = j >> 7, c = j & 127;
        float s = 0.f;
        #pragma unroll
        for (int dk = 0; dk < 4; dk++) s = fmaf(Qm[h * 4 + dk], w_k[(h * 4 + dk) * 128 + c], s);
        qkG[j] = s;
    } else if (i < 67600) {
        int h = i - 67584;
        float s = 0.f;
        #pragma unroll
        for (int dk = 0; dk < 4; dk++) s = fmaf(Qm[h * 4 + dk], b_k[h * 4 + dk], s);
        qbG[h] = s;
    }
}

// ---------------- main fused kernel: 2 pixels per block ----------------
constexpr int A_ELEMS = 48 * 136;   // per hi/lo array (fp16)
constexpr int H_ELEMS = 48 * 264;
constexpr int A_BYTES = 2 * A_ELEMS * 2;   // 26112
constexpr int H_BYTES = 2 * H_ELEMS * 2;   // 50688

__global__ __launch_bounds__(256, 2) void ltae_main(
    const float* __restrict__ x, const int* __restrict__ bpos,
    const float* __restrict__ b_in0, const float* __restrict__ g_in0, const float* __restrict__ be_in0,
    const float* __restrict__ b_in1, const float* __restrict__ g_in1, const float* __restrict__ be_in1,
    const float* __restrict__ g_innorm, const float* __restrict__ b_innorm,
    const float* __restrict__ w_m0, const float* __restrict__ b_m0,
    const float* __restrict__ g_m0, const float* __restrict__ be_m0,
    const float* __restrict__ w_m1, const float* __restrict__ b_m1,
    const float* __restrict__ g_m1, const float* __restrict__ be_m1,
    const float* __restrict__ g_out, const float* __restrict__ b_out,
    const _Float16* __restrict__ w1h, const _Float16* __restrict__ w1l,
    const _Float16* __restrict__ w2h, const _Float16* __restrict__ w2l,
    const float* __restrict__ qkG, const float* __restrict__ qbG,
    float* __restrict__ out)
{
    __shared__ __align__(16) unsigned char smem[A_BYTES + H_BYTES];
    _Float16* Ah = (_Float16*)smem;            // [48][136]
    _Float16* Al = Ah + A_ELEMS;
    _Float16* Hh = (_Float16*)(smem + A_BYTES); // [48][264]
    _Float16* Hl = Hh + H_ELEMS;
    float* xs2 = (float*)smem;                  // [48][132] fp32, overlays A after GEMM2
    float* scP = (float*)(smem + A_BYTES);      // [2][16][24] overlays H after GEMM2
    float* ovP = scP + 768;                     // [2][128]
    float* mmP = ovP + 256;                     // [2][256]
    float* ysP = ovP;                           // reuse

    __shared__ float peS[24][8];
    __shared__ float muS[2][16], rsS[2][16];
    __shared__ float gS[128], bnS[128];

    const int tid = threadIdx.x;
    const int bid = blockIdx.x;
    const int sb  = (bid & 7) * 576 + (bid >> 3);   // bijective XCD swizzle (4608 % 8 == 0)
    const int b   = sb / 1152;
    const int pixbase = (sb - b * 1152) * 2;

    // ---- Phase 0: PE table, gamma cache, gather x -> Ah/Al (split fp16) ----
    if (tid < 192) {
        int t = tid >> 3, d = tid & 7;
        const float dens[4] = {1.0f, 5.623413251903491f, 31.622776601683793f, 177.82794100389228f};
        float ang = (float)bpos[b * 24 + t] / dens[d >> 1];
        peS[t][d] = (d & 1) ? cosf(ang) : sinf(ang);
    }
    if (tid < 128) { gS[tid] = g_innorm[tid]; bnS[tid] = b_innorm[tid]; }
    for (int i = tid; i < 24 * 128; i += 256) {
        int t = i >> 7, c = i & 127;
        const float* gp = x + ((size_t)((b * 24 + t) * 128 + c)) * HWp + pixbase;
        float2 v = *(const float2*)gp;
        _Float16 h0 = (_Float16)v.x;
        _Float16 h1 = (_Float16)v.y;
        Ah[(0 * 24 + t) * 136 + c] = h0;
        Al[(0 * 24 + t) * 136 + c] = (_Float16)(v.x - (float)h0);
        Ah[(1 * 24 + t) * 136 + c] = h1;
        Al[(1 * 24 + t) * 136 + c] = (_Float16)(v.y - (float)h1);
    }
    __syncthreads();

    const int w  = tid >> 6;
    const int l  = tid & 63;
    const int lr = l & 15;
    const int lg = l >> 4;

    // ---- GEMM1: (48x128)@(128->256) split-fp16 MFMA + bias + GN(4/64) + ReLU -> Hh/Hl ----
    {
        f16x8 bh[4][4], bl[4][4];
        float gg[4], bb[4], bi[4];
        #pragma unroll
        for (int nt = 0; nt < 4; nt++) {
            int n = w * 64 + nt * 16 + lr;
            #pragma unroll
            for (int ks = 0; ks < 4; ks++) {
                bh[nt][ks] = *(const f16x8*)(w1h + n * 128 + ks * 32 + lg * 8);
                bl[nt][ks] = *(const f16x8*)(w1l + n * 128 + ks * 32 + lg * 8);
            }
            gg[nt] = g_in0[n]; bb[nt] = be_in0[n]; bi[nt] = b_in0[n];
        }
        for (int m = 0; m < 3; m++) {
            f32x4 acc[4];
            #pragma unroll
            for (int nt = 0; nt < 4; nt++) acc[nt] = f32x4{0.f, 0.f, 0.f, 0.f};
            #pragma unroll
            for (int ks = 0; ks < 4; ks++) {
                f16x8 ah = *(const f16x8*)&Ah[(m * 16 + lr) * 136 + ks * 32 + lg * 8];
                f16x8 al = *(const f16x8*)&Al[(m * 16 + lr) * 136 + ks * 32 + lg * 8];
                #pragma unroll
                for (int nt = 0; nt < 4; nt++) {
                    acc[nt] = __builtin_amdgcn_mfma_f32_16x16x32_f16(ah, bl[nt][ks], acc[nt], 0, 0, 0);
                    acc[nt] = __builtin_amdgcn_mfma_f32_16x16x32_f16(al, bh[nt][ks], acc[nt], 0, 0, 0);
                    acc[nt] = __builtin_amdgcn_mfma_f32_16x16x32_f16(ah, bh[nt][ks], acc[nt], 0, 0, 0);
                }
            }
            #pragma unroll
            for (int r = 0; r < 4; r++) {
                float s = 0.f, s2 = 0.f;
                #pragma unroll
                for (int nt = 0; nt < 4; nt++) {
                    float v = acc[nt][r] + bi[nt]; s += v; s2 += v * v;
                }
                #pragma unroll
                for (int mk = 1; mk <= 8; mk <<= 1) { s += __shfl_xor(s, mk); s2 += __shfl_xor(s2, mk); }
                float mu = s * (1.f / 64.f);
                float rs = rsqrtf(s2 * (1.f / 64.f) - mu * mu + EPS);
                int row = m * 16 + lg * 4 + r;
                #pragma unroll
                for (int nt = 0; nt < 4; nt++) {
                    float v = acc[nt][r] + bi[nt];
                    float hv = fmaxf(fmaf((v - mu) * rs, gg[nt], bb[nt]), 0.f);
                    _Float16 hh = (_Float16)hv;
                    int idx = row * 264 + w * 64 + nt * 16 + lr;
                    Hh[idx] = hh;
                    Hl[idx] = (_Float16)(hv - (float)hh);
                }
            }
        }
    }
    __syncthreads();

    // ---- GEMM2: (48x256)@(256->128) split-fp16 MFMA + bias + GN(4/32) + ReLU -> xs2 (fp32) ----
    {
        f16x8 bh[2][8], bl[2][8];
        float gg[2], bb[2], bi[2];
        #pragma unroll
        for (int nt = 0; nt < 2; nt++) {
            int n = w * 32 + nt * 16 + lr;
            #pragma unroll
            for (int ks = 0; ks < 8; ks++) {
                bh[nt][ks] = *(const f16x8*)(w2h + n * 256 + ks * 32 + lg * 8);
                bl[nt][ks] = *(const f16x8*)(w2l + n * 256 + ks * 32 + lg * 8);
            }
            gg[nt] = g_in1[n]; bb[nt] = be_in1[n]; bi[nt] = b_in1[n];
        }
        for (int m = 0; m < 3; m++) {
            f32x4 acc0 = f32x4{0.f, 0.f, 0.f, 0.f};
            f32x4 acc1 = f32x4{0.f, 0.f, 0.f, 0.f};
            #pragma unroll
            for (int ks = 0; ks < 8; ks++) {
                f16x8 ah = *(const f16x8*)&Hh[(m * 16 + lr) * 264 + ks * 32 + lg * 8];
                f16x8 al = *(const f16x8*)&Hl[(m * 16 + lr) * 264 + ks * 32 + lg * 8];
                acc0 = __builtin_amdgcn_mfma_f32_16x16x32_f16(ah, bl[0][ks], acc0, 0, 0, 0);
                acc0 = __builtin_amdgcn_mfma_f32_16x16x32_f16(al, bh[0][ks], acc0, 0, 0, 0);
                acc0 = __builtin_amdgcn_mfma_f32_16x16x32_f16(ah, bh[0][ks], acc0, 0, 0, 0);
                acc1 = __builtin_amdgcn_mfma_f32_16x16x32_f16(ah, bl[1][ks], acc1, 0, 0, 0);
                acc1 = __builtin_amdgcn_mfma_f32_16x16x32_f16(al, bh[1][ks], acc1, 0, 0, 0);
                acc1 = __builtin_amdgcn_mfma_f32_16x16x32_f16(ah, bh[1][ks], acc1, 0, 0, 0);
            }
            #pragma unroll
            for (int r = 0; r < 4; r++) {
                float v0 = acc0[r] + bi[0], v1 = acc1[r] + bi[1];
                float s = v0 + v1, s2 = v0 * v0 + v1 * v1;
                #pragma unroll
                for (int mk = 1; mk <= 8; mk <<= 1) { s += __shfl_xor(s, mk); s2 += __shfl_xor(s2, mk); }
                float mu = s * (1.f / 32.f);
                float rs = rsqrtf(s2 * (1.f / 32.f) - mu * mu + EPS);
                int row = m * 16 + lg * 4 + r;
                xs2[row * 132 + w * 32 + lr]      = fmaxf(fmaf((v0 - mu) * rs, gg[0], bb[0]), 0.f);
                xs2[row * 132 + w * 32 + 16 + lr] = fmaxf(fmaf((v1 - mu) * rs, gg[1], bb[1]), 0.f);
            }
        }
    }
    __syncthreads();

    // ---- Phase 3: in_norm GN(16 over C,T) + PE (fp32). 2 waves per pixel. ----
    {
        const int p = w >> 1, hw = w & 1;
        int g = hw * 8 + (l >> 3), j = l & 7;
        float s = 0.f, s2 = 0.f;
        #pragma unroll
        for (int k = 0; k < 24; k++) {
            int e = j + 8 * k;                 // 0..191
            int t = e >> 3, co = e & 7;
            float v = xs2[(p * 24 + t) * 132 + g * 8 + co];
            s += v; s2 += v * v;
        }
        s += __shfl_xor(s, 1);  s += __shfl_xor(s, 2);  s += __shfl_xor(s, 4);
        s2 += __shfl_xor(s2, 1); s2 += __shfl_xor(s2, 2); s2 += __shfl_xor(s2, 4);
        if (j == 0) {
            float mu = s * (1.f / 192.f);
            muS[p][g] = mu;
            rsS[p][g] = rsqrtf(s2 * (1.f / 192.f) - mu * mu + EPS);
        }
    }
    __syncthreads();
    for (int i = tid; i < 48 * 128; i += 256) {
        int row = i >> 7, c = i & 127;
        int p = row >= 24 ? 1 : 0;
        int t = row - p * 24;
        int idx = row * 132 + c;
        xs2[idx] = (xs2[idx] - muS[p][c >> 3]) * rsS[p][c >> 3] * gS[c] + bnS[c] + peS[t][c & 7];
    }
    __syncthreads();

    // ---- Phase 4: scores (fp32, folded Q·K) ----
    #pragma unroll
    for (int j = 0; j < 3; j++) {
        int idx = tid + 256 * j;               // 0..767
        int p = idx >= 384 ? 1 : 0;
        int r2 = idx - p * 384;
        int h = r2 / 24, t = r2 - h * 24;
        float s = qbG[h];
        #pragma unroll
        for (int c = 0; c < 128; c += 4) {
            float4 a4 = *(const float4*)&xs2[(p * 24 + t) * 132 + c];
            float4 q4 = *(const float4*)(qkG + h * 128 + c);
            s = fmaf(a4.x, q4.x, s); s = fmaf(a4.y, q4.y, s);
            s = fmaf(a4.z, q4.z, s); s = fmaf(a4.w, q4.w, s);
        }
        scP[(p * 16 + h) * 24 + t] = 0.5f * s;
    }
    __syncthreads();

    // ---- softmax: wave w handles pixel w>>1, heads (w&1)*8 + l>>3 ----
    {
        const int p = w >> 1;
        int h = (w & 1) * 8 + (l >> 3), j = l & 7;
        float* sp = scP + (p * 16 + h) * 24;
        float mx = -1e30f;
        #pragma unroll
        for (int k = 0; k < 3; k++) mx = fmaxf(mx, sp[j + 8 * k]);
        mx = fmaxf(mx, __shfl_xor(mx, 1));
        mx = fmaxf(mx, __shfl_xor(mx, 2));
        mx = fmaxf(mx, __shfl_xor(mx, 4));
        float ev[3], sum = 0.f;
        #pragma unroll
        for (int k = 0; k < 3; k++) { ev[k] = __expf(sp[j + 8 * k] - mx); sum += ev[k]; }
        sum += __shfl_xor(sum, 1);
        sum += __shfl_xor(sum, 2);
        sum += __shfl_xor(sum, 4);
        float inv = 1.f / sum;
        #pragma unroll
        for (int k = 0; k < 3; k++) sp[j + 8 * k] = ev[k] * inv;
    }

    // ---- Phase 5: o = a . v (same wave produced these heads' probs) ----
    {
        const int p = w >> 1;
        int ch = (w & 1) * 64 + l;
        int h = ch >> 3;
        float s = 0.f;
        const float* sp = scP + (p * 16 + h) * 24;
        #pragma unroll
        for (int t = 0; t < 24; t++)
            s = fmaf(sp[t], xs2[(p * 24 + t) * 132 + ch], s);
        ovP[p * 128 + ch] = s;
    }
    __syncthreads();

    // ---- Phase 6: MLP layer 1 (128->256) + GN(4/64) + ReLU ----
    {
        const int o = tid;
        const float* wr = w_m0 + o * 128;
        float acc[2] = {0.f, 0.f};
        for (int c0 = 0; c0 < 128; c0 += 4) {
            float4 w4 = *(const float4*)(wr + c0);
            #pragma unroll
            for (int pp = 0; pp < 2; pp++) {
                float4 x4 = *(const float4*)(ovP + pp * 128 + c0);
                acc[pp] = fmaf(w4.x, x4.x, acc[pp]); acc[pp] = fmaf(w4.y, x4.y, acc[pp]);
                acc[pp] = fmaf(w4.z, x4.z, acc[pp]); acc[pp] = fmaf(w4.w, x4.w, acc[pp]);
            }
        }
        float bi = b_m0[o], gg = g_m0[o], bb = be_m0[o];
        #pragma unroll
        for (int pp = 0; pp < 2; pp++) {
            float v = acc[pp] + bi;
            float s = v, s2 = v * v;
            #pragma unroll
            for (int mk = 1; mk <= 32; mk <<= 1) { s += __shfl_xor(s, mk); s2 += __shfl_xor(s2, mk); }
            float mu = s * (1.f / 64.f);
            float rs = rsqrtf(s2 * (1.f / 64.f) - mu * mu + EPS);
            mmP[pp * 256 + o] = fmaxf(fmaf((v - mu) * rs, gg, bb), 0.f);
        }
    }
    __syncthreads();

    // ---- Phase 7: MLP layer 2 (256->128) + GN(4/32) + ReLU + out_norm GN(16/8) ----
    {
        const int o = tid & 127, pp = tid >> 7;
        const float* wr = w_m1 + o * 256;
        float acc = 0.f;
        for (int c0 = 0; c0 < 256; c0 += 4) {
            float4 w4 = *(const float4*)(wr + c0);
            float4 x4 = *(const float4*)(mmP + pp * 256 + c0);
            acc = fmaf(w4.x, x4.x, acc); acc = fmaf(w4.y, x4.y, acc);
            acc = fmaf(w4.z, x4.z, acc); acc = fmaf(w4.w, x4.w, acc);
        }
        float v = acc + b_m1[o];
        float s = v, s2 = v * v;
        #pragma unroll
        for (int mk = 1; mk <= 16; mk <<= 1) { s += __shfl_xor(s, mk); s2 += __shfl_xor(s2, mk); }
        float mu = s * (1.f / 32.f);
        float rs = rsqrtf(s2 * (1.f / 32.f) - mu * mu + EPS);
        float v2 = fmaxf(fmaf((v - mu) * rs, g_m1[o], be_m1[o]), 0.f);
        float t1 = v2, t2 = v2 * v2;
        #pragma unroll
        for (int mk = 1; mk <= 4; mk <<= 1) { t1 += __shfl_xor(t1, mk); t2 += __shfl_xor(t2, mk); }
        float mu2 = t1 * (1.f / 8.f);
        float rs2 = rsqrtf(t2 * (1.f / 8.f) - mu2 * mu2 + EPS);
        ysP[pp * 128 + o] = fmaf((v2 - mu2) * rs2, g_out[o], b_out[o]);
    }
    __syncthreads();

    // ---- Phase 8: store (float2 across the 2 pixels) ----
    if (tid < 128) {
        float2 y2;
        y2.x = ysP[0 * 128 + tid];
        y2.y = ysP[1 * 128 + tid];
        *(float2*)(out + ((size_t)(b * 128 + tid)) * HWp + pixbase) = y2;
    }
}

extern "C" void kernel_launch(void* const* d_in, const int* in_sizes, int n_in,
                              void* d_out, int out_size, void* d_ws, size_t ws_size,
                              hipStream_t stream) {
    const float* x        = (const float*)d_in[0];
    const int*   bpos     = (const int*)  d_in[1];
    const float* w_in0    = (const float*)d_in[2];
    const float* b_in0    = (const float*)d_in[3];
    const float* g_in0    = (const float*)d_in[4];
    const float* be_in0   = (const float*)d_in[5];
    const float* w_in1    = (const float*)d_in[6];
    const float* b_in1    = (const float*)d_in[7];
    const float* g_in1    = (const float*)d_in[8];
    const float* be_in1   = (const float*)d_in[9];
    const float* g_innorm = (const float*)d_in[10];
    const float* b_innorm = (const float*)d_in[11];
    const float* Qm       = (const float*)d_in[12];
    const float* w_k      = (const float*)d_in[13];
    const float* b_k      = (const float*)d_in[14];
    const float* w_m0     = (const float*)d_in[15];
    const float* b_m0     = (const float*)d_in[16];
    const float* g_m0     = (const float*)d_in[17];
    const float* be_m0    = (const float*)d_in[18];
    const float* w_m1     = (const float*)d_in[19];
    const float* b_m1     = (const float*)d_in[20];
    const float* g_m1     = (const float*)d_in[21];
    const float* be_m1    = (const float*)d_in[22];
    const float* g_out    = (const float*)d_in[23];
    const float* b_out    = (const float*)d_in[24];

    // ws layout (bytes): w1h@0, w1l@65536, w2h@131072, w2l@196608 (fp16, 32768 each)
    //                    qk@262144 (2048 f32), qb@270336 (16 f32)
    _Float16* w1h = (_Float16*)d_ws;
    _Float16* w1l = w1h + 32768;
    _Float16* w2h = w1l + 32768;
    _Float16* w2l = w2h + 32768;
    float*    qkG = (float*)((char*)d_ws + 262144);
    float*    qbG = qkG + 2048;

    hipLaunchKernelGGL(ltae_prep, dim3(265), dim3(256), 0, stream,
                       w_in0, w_in1, Qm, w_k, b_k, w1h, w1l, w2h, w2l, qkG, qbG);

    hipLaunchKernelGGL(ltae_main, dim3(4608), dim3(256), 0, stream,
                       x, bpos,
                       b_in0, g_in0, be_in0,
                       b_in1, g_in1, be_in1,
                       g_innorm, b_innorm,
                       w_m0, b_m0, g_m0, be_m0,
                       w_m1, b_m1, g_m1, be_m1,
                       g_out, b_out,
                       w1h, w1l, w2h, w2l, qkG, qbG,
                       (float*)d_out);
}

// Round 4
// 444.124 us; speedup vs baseline: 2.4266x; 1.0890x over previous
//
#include <hip/hip_runtime.h>
#include <math.h>

typedef _Float16 f16x8 __attribute__((ext_vector_type(8)));
typedef float f32x4 __attribute__((ext_vector_type(4)));

constexpr int HWp = 2304;
constexpr float EPS = 1e-5f;

// swizzled fp16 index into a [48][128] tile with 256B rows:
// byte = row*256 + ((c*2) ^ ((row&7)<<4)); return fp16 index
__device__ __forceinline__ int sidx(int row, int c) {
    return ((row << 8) + ((c << 1) ^ ((row & 7) << 4))) >> 1;
}

// ---------------- prep: weights -> split fp16 (hi/lo), fold Q+scale into w_k ----------------
__global__ void ltae_prep(const float* __restrict__ w_in0, const float* __restrict__ w_in1,
                          const float* __restrict__ Qm, const float* __restrict__ w_k,
                          const float* __restrict__ b_k,
                          _Float16* __restrict__ w1h, _Float16* __restrict__ w1l,
                          _Float16* __restrict__ w2h, _Float16* __restrict__ w2l,
                          _Float16* __restrict__ qkBh, _Float16* __restrict__ qkBl,
                          float* __restrict__ qb2G) {
    int i = blockIdx.x * 256 + threadIdx.x;
    if (i < 32768) {
        float v = w_in0[i];
        _Float16 h = (_Float16)v;
        w1h[i] = h; w1l[i] = (_Float16)(v - (float)h);
    } else if (i < 65536) {
        int j = i - 32768;
        float v = w_in1[j];
        _Float16 h = (_Float16)v;
        w2h[j] = h; w2l[j] = (_Float16)(v - (float)h);
    } else if (i < 67584) {
        int j = i - 65536; int h = j >> 7, k = j & 127;
        float s = 0.f;
        #pragma unroll
        for (int dk = 0; dk < 4; dk++) s = fmaf(Qm[h * 4 + dk], w_k[(h * 4 + dk) * 128 + k], s);
        s *= 0.5f;                      // fold 1/sqrt(d_k)
        _Float16 hi = (_Float16)s;
        int ks = k >> 5, lg = (k >> 3) & 3, jj = k & 7;
        int pos = ((ks * 4 + lg) * 16 + h) * 8 + jj;   // B-fragment layout
        qkBh[pos] = hi; qkBl[pos] = (_Float16)(s - (float)hi);
    } else if (i < 67600) {
        int h = i - 67584;
        float s = 0.f;
        #pragma unroll
        for (int dk = 0; dk < 4; dk++) s = fmaf(Qm[h * 4 + dk], b_k[h * 4 + dk], s);
        qb2G[h] = 0.5f * s;
    }
}

// ---------------- main fused kernel: 2 pixels per block, 3 blocks/CU ----------------
__global__ __launch_bounds__(256, 3) void ltae_main(
    const float* __restrict__ x, const int* __restrict__ bpos,
    const float* __restrict__ b_in0, const float* __restrict__ g_in0, const float* __restrict__ be_in0,
    const float* __restrict__ b_in1, const float* __restrict__ g_in1, const float* __restrict__ be_in1,
    const float* __restrict__ g_innorm, const float* __restrict__ b_innorm,
    const float* __restrict__ w_m0, const float* __restrict__ b_m0,
    const float* __restrict__ g_m0, const float* __restrict__ be_m0,
    const float* __restrict__ w_m1, const float* __restrict__ b_m1,
    const float* __restrict__ g_m1, const float* __restrict__ be_m1,
    const float* __restrict__ g_out, const float* __restrict__ b_out,
    const _Float16* __restrict__ w1h, const _Float16* __restrict__ w1l,
    const _Float16* __restrict__ w2h, const _Float16* __restrict__ w2l,
    const _Float16* __restrict__ qkBh, const _Float16* __restrict__ qkBl,
    const float* __restrict__ qb2G,
    float* __restrict__ out)
{
    __shared__ __align__(16) _Float16 Ah[48 * 128], Al[48 * 128];  // tokens, later xs2 hi/lo
    __shared__ __align__(16) _Float16 Hh[48 * 128], Hl[48 * 128];  // h1 half-tile hi/lo
    __shared__ float peS[24][8];
    __shared__ float muS[2][16], rsS[2][16];
    __shared__ float gS[128], bnS[128];
    __shared__ float2 partS[192];     // GEMM1 cross-wave GN partials [w][m][lg][r]

    float* scP = (float*)Hh;          // [2][16][24] overlays H after GEMMs
    float* ovP = scP + 768;           // [2][128]
    float* mmP = ovP + 256;           // [2][256]
    float* ysP = ovP;

    const int tid = threadIdx.x;
    const int bid = blockIdx.x;
    const int sb  = (bid & 7) * 576 + (bid >> 3);   // bijective XCD swizzle (4608 % 8 == 0)
    const int b   = sb / 1152;
    const int pixbase = (sb - b * 1152) * 2;

    // ---- Phase 0: PE table, gamma cache, gather x -> Ah/Al (split fp16, swizzled) ----
    if (tid < 192) {
        int t = tid >> 3, d = tid & 7;
        const float dens[4] = {1.0f, 5.623413251903491f, 31.622776601683793f, 177.82794100389228f};
        float ang = (float)bpos[b * 24 + t] / dens[d >> 1];
        peS[t][d] = (d & 1) ? cosf(ang) : sinf(ang);
    }
    if (tid < 128) { gS[tid] = g_innorm[tid]; bnS[tid] = b_innorm[tid]; }
    for (int i = tid; i < 24 * 128; i += 256) {
        int t = i >> 7, c = i & 127;
        const float* gp = x + ((size_t)((b * 24 + t) * 128 + c)) * HWp + pixbase;
        float2 v = *(const float2*)gp;
        _Float16 h0 = (_Float16)v.x;
        _Float16 h1 = (_Float16)v.y;
        int i0 = sidx(t, c), i1 = sidx(24 + t, c);
        Ah[i0] = h0; Al[i0] = (_Float16)(v.x - (float)h0);
        Ah[i1] = h1; Al[i1] = (_Float16)(v.y - (float)h1);
    }
    __syncthreads();

    const int w  = tid >> 6;
    const int l  = tid & 63;
    const int lr = l & 15;
    const int lg = l >> 4;

    // ---- GEMM1 (two N-halves) + GEMM2 (partial-accumulate over K-halves) ----
    f32x4 g2acc[3][2];
    #pragma unroll
    for (int m = 0; m < 3; m++)
        #pragma unroll
        for (int nt = 0; nt < 2; nt++) g2acc[m][nt] = f32x4{0.f, 0.f, 0.f, 0.f};

    #pragma unroll 1
    for (int half = 0; half < 2; half++) {
        // --- GEMM1 half: output channels half*128 + [0,128); wave w owns 32 ch ---
        f16x8 bh[2][4], bl[2][4];
        float gg[2], bb[2], bi[2];
        #pragma unroll
        for (int nt = 0; nt < 2; nt++) {
            int n = half * 128 + w * 32 + nt * 16 + lr;
            #pragma unroll
            for (int ks = 0; ks < 4; ks++) {
                bh[nt][ks] = *(const f16x8*)(w1h + n * 128 + ks * 32 + lg * 8);
                bl[nt][ks] = *(const f16x8*)(w1l + n * 128 + ks * 32 + lg * 8);
            }
            gg[nt] = g_in0[n]; bb[nt] = be_in0[n]; bi[nt] = b_in0[n];
        }
        f32x4 acc[3][2];
        #pragma unroll
        for (int m = 0; m < 3; m++)
            #pragma unroll
            for (int nt = 0; nt < 2; nt++) acc[m][nt] = f32x4{0.f, 0.f, 0.f, 0.f};
        #pragma unroll
        for (int m = 0; m < 3; m++) {
            #pragma unroll
            for (int ks = 0; ks < 4; ks++) {
                f16x8 ah = *(const f16x8*)&Ah[sidx(m * 16 + lr, ks * 32 + lg * 8)];
                f16x8 al = *(const f16x8*)&Al[sidx(m * 16 + lr, ks * 32 + lg * 8)];
                #pragma unroll
                for (int nt = 0; nt < 2; nt++) {
                    acc[m][nt] = __builtin_amdgcn_mfma_f32_16x16x32_f16(ah, bl[nt][ks], acc[m][nt], 0, 0, 0);
                    acc[m][nt] = __builtin_amdgcn_mfma_f32_16x16x32_f16(al, bh[nt][ks], acc[m][nt], 0, 0, 0);
                    acc[m][nt] = __builtin_amdgcn_mfma_f32_16x16x32_f16(ah, bh[nt][ks], acc[m][nt], 0, 0, 0);
                }
            }
        }
        // cross-wave GN(4/64) partials: wave pair {w, w^1} shares a group
        float ps[3][4], ps2[3][4];
        #pragma unroll
        for (int m = 0; m < 3; m++) {
            #pragma unroll
            for (int r = 0; r < 4; r++) {
                float v0 = acc[m][0][r] + bi[0], v1 = acc[m][1][r] + bi[1];
                float s = v0 + v1, s2 = v0 * v0 + v1 * v1;
                #pragma unroll
                for (int mk = 1; mk <= 8; mk <<= 1) { s += __shfl_xor(s, mk); s2 += __shfl_xor(s2, mk); }
                ps[m][r] = s; ps2[m][r] = s2;
            }
        }
        if (lr == 0) {
            #pragma unroll
            for (int m = 0; m < 3; m++)
                #pragma unroll
                for (int r = 0; r < 4; r++)
                    partS[w * 48 + m * 16 + lg * 4 + r] = make_float2(ps[m][r], ps2[m][r]);
        }
        __syncthreads();
        #pragma unroll
        for (int m = 0; m < 3; m++) {
            #pragma unroll
            for (int r = 0; r < 4; r++) {
                float2 q = partS[(w ^ 1) * 48 + m * 16 + lg * 4 + r];
                float st = ps[m][r] + q.x, s2t = ps2[m][r] + q.y;
                float mu = st * (1.f / 64.f);
                float rs = rsqrtf(s2t * (1.f / 64.f) - mu * mu + EPS);
                int row = m * 16 + lg * 4 + r;
                #pragma unroll
                for (int nt = 0; nt < 2; nt++) {
                    float v = acc[m][nt][r] + bi[nt];
                    float hv = fmaxf(fmaf((v - mu) * rs, gg[nt], bb[nt]), 0.f);
                    _Float16 h16 = (_Float16)hv;
                    int ii = sidx(row, w * 32 + nt * 16 + lr);
                    Hh[ii] = h16;
                    Hl[ii] = (_Float16)(hv - (float)h16);
                }
            }
        }
        __syncthreads();

        // --- GEMM2 part: K in [half*128, half*128+128), accumulate into g2acc ---
        f16x8 b2h[2][4], b2l[2][4];
        #pragma unroll
        for (int nt = 0; nt < 2; nt++) {
            int n = w * 32 + nt * 16 + lr;
            #pragma unroll
            for (int ks = 0; ks < 4; ks++) {
                b2h[nt][ks] = *(const f16x8*)(w2h + n * 256 + half * 128 + ks * 32 + lg * 8);
                b2l[nt][ks] = *(const f16x8*)(w2l + n * 256 + half * 128 + ks * 32 + lg * 8);
            }
        }
        #pragma unroll
        for (int m = 0; m < 3; m++) {
            #pragma unroll
            for (int ks = 0; ks < 4; ks++) {
                f16x8 ah = *(const f16x8*)&Hh[sidx(m * 16 + lr, ks * 32 + lg * 8)];
                f16x8 al = *(const f16x8*)&Hl[sidx(m * 16 + lr, ks * 32 + lg * 8)];
                #pragma unroll
                for (int nt = 0; nt < 2; nt++) {
                    g2acc[m][nt] = __builtin_amdgcn_mfma_f32_16x16x32_f16(ah, b2l[nt][ks], g2acc[m][nt], 0, 0, 0);
                    g2acc[m][nt] = __builtin_amdgcn_mfma_f32_16x16x32_f16(al, b2h[nt][ks], g2acc[m][nt], 0, 0, 0);
                    g2acc[m][nt] = __builtin_amdgcn_mfma_f32_16x16x32_f16(ah, b2h[nt][ks], g2acc[m][nt], 0, 0, 0);
                }
            }
        }
        __syncthreads();   // H (and partS) free for next half
    }

    // ---- GEMM2 epilogue: bias + GN(4/32, wave-local) + ReLU -> xs2 hi/lo (A region) ----
    {
        float gg2[2], bb2[2], bi2[2];
        #pragma unroll
        for (int nt = 0; nt < 2; nt++) {
            int n = w * 32 + nt * 16 + lr;
            gg2[nt] = g_in1[n]; bb2[nt] = be_in1[n]; bi2[nt] = b_in1[n];
        }
        #pragma unroll
        for (int m = 0; m < 3; m++) {
            #pragma unroll
            for (int r = 0; r < 4; r++) {
                float v0 = g2acc[m][0][r] + bi2[0], v1 = g2acc[m][1][r] + bi2[1];
                float s = v0 + v1, s2 = v0 * v0 + v1 * v1;
                #pragma unroll
                for (int mk = 1; mk <= 8; mk <<= 1) { s += __shfl_xor(s, mk); s2 += __shfl_xor(s2, mk); }
                float mu = s * (1.f / 32.f);
                float rs = rsqrtf(s2 * (1.f / 32.f) - mu * mu + EPS);
                int row = m * 16 + lg * 4 + r;
                float h0 = fmaxf(fmaf((v0 - mu) * rs, gg2[0], bb2[0]), 0.f);
                float h1v = fmaxf(fmaf((v1 - mu) * rs, gg2[1], bb2[1]), 0.f);
                _Float16 p0 = (_Float16)h0, p1 = (_Float16)h1v;
                int i0 = sidx(row, w * 32 + lr), i1 = sidx(row, w * 32 + 16 + lr);
                Ah[i0] = p0; Al[i0] = (_Float16)(h0 - (float)p0);
                Ah[i1] = p1; Al[i1] = (_Float16)(h1v - (float)p1);
            }
        }
    }
    __syncthreads();

    // ---- Phase 3: in_norm GN(16 over C,T) stats ----
    {
        const int p = w >> 1, hw = w & 1;
        int g = hw * 8 + (l >> 3), j = l & 7;
        float s = 0.f, s2 = 0.f;
        #pragma unroll
        for (int k = 0; k < 24; k++) {
            int e = j + 8 * k;                 // 0..191
            int t = e >> 3, co = e & 7;
            int ii = sidx(p * 24 + t, g * 8 + co);
            float v = (float)Ah[ii] + (float)Al[ii];
            s += v; s2 += v * v;
        }
        s += __shfl_xor(s, 1);  s += __shfl_xor(s, 2);  s += __shfl_xor(s, 4);
        s2 += __shfl_xor(s2, 1); s2 += __shfl_xor(s2, 2); s2 += __shfl_xor(s2, 4);
        if (j == 0) {
            float mu = s * (1.f / 192.f);
            muS[p][g] = mu;
            rsS[p][g] = rsqrtf(s2 * (1.f / 192.f) - mu * mu + EPS);
        }
    }
    __syncthreads();
    // apply norm + PE, rewrite hi/lo
    for (int i = tid; i < 48 * 128; i += 256) {
        int row = i >> 7, c = i & 127;
        int p = row >= 24 ? 1 : 0;
        int t = row - p * 24;
        int ii = sidx(row, c);
        float v = (float)Ah[ii] + (float)Al[ii];
        v = (v - muS[p][c >> 3]) * rsS[p][c >> 3] * gS[c] + bnS[c] + peS[t][c & 7];
        _Float16 h16 = (_Float16)v;
        Ah[ii] = h16; Al[ii] = (_Float16)(v - (float)h16);
    }
    __syncthreads();

    // ---- Phase 4: scores via split-fp16 MFMA (waves 0..2, m-tile each) ----
    if (w < 3) {
        const int m = w;
        f16x8 qh[4], ql[4];
        #pragma unroll
        for (int ks = 0; ks < 4; ks++) {
            qh[ks] = *(const f16x8*)(qkBh + ((ks * 4 + lg) * 16 + lr) * 8);
            ql[ks] = *(const f16x8*)(qkBl + ((ks * 4 + lg) * 16 + lr) * 8);
        }
        f32x4 sacc = f32x4{0.f, 0.f, 0.f, 0.f};
        #pragma unroll
        for (int ks = 0; ks < 4; ks++) {
            f16x8 ah = *(const f16x8*)&Ah[sidx(m * 16 + lr, ks * 32 + lg * 8)];
            f16x8 al = *(const f16x8*)&Al[sidx(m * 16 + lr, ks * 32 + lg * 8)];
            sacc = __builtin_amdgcn_mfma_f32_16x16x32_f16(ah, ql[ks], sacc, 0, 0, 0);
            sacc = __builtin_amdgcn_mfma_f32_16x16x32_f16(al, qh[ks], sacc, 0, 0, 0);
            sacc = __builtin_amdgcn_mfma_f32_16x16x32_f16(ah, qh[ks], sacc, 0, 0, 0);
        }
        float qb = qb2G[lr];
        #pragma unroll
        for (int r = 0; r < 4; r++) {
            int row = m * 16 + lg * 4 + r;
            int p = row >= 24 ? 1 : 0;
            int t = row - p * 24;
            scP[(p * 16 + lr) * 24 + t] = sacc[r] + qb;
        }
    }
    __syncthreads();

    // ---- softmax: wave w -> pixel w>>1, heads (w&1)*8 + l>>3 ----
    {
        const int p = w >> 1;
        int h = (w & 1) * 8 + (l >> 3), j = l & 7;
        float* sp = scP + (p * 16 + h) * 24;
        float mx = -1e30f;
        #pragma unroll
        for (int k = 0; k < 3; k++) mx = fmaxf(mx, sp[j + 8 * k]);
        mx = fmaxf(mx, __shfl_xor(mx, 1));
        mx = fmaxf(mx, __shfl_xor(mx, 2));
        mx = fmaxf(mx, __shfl_xor(mx, 4));
        float ev[3], sum = 0.f;
        #pragma unroll
        for (int k = 0; k < 3; k++) { ev[k] = __expf(sp[j + 8 * k] - mx); sum += ev[k]; }
        sum += __shfl_xor(sum, 1);
        sum += __shfl_xor(sum, 2);
        sum += __shfl_xor(sum, 4);
        float inv = 1.f / sum;
        #pragma unroll
        for (int k = 0; k < 3; k++) sp[j + 8 * k] = ev[k] * inv;
    }

    // ---- Phase 5: o = a . v (wave-local heads) ----
    {
        const int p = w >> 1;
        int ch = (w & 1) * 64 + l;
        int h = ch >> 3;
        const float* sp = scP + (p * 16 + h) * 24;
        float s = 0.f;
        #pragma unroll
        for (int t = 0; t < 24; t++) {
            int ii = sidx(p * 24 + t, ch);
            s = fmaf(sp[t], (float)Ah[ii] + (float)Al[ii], s);
        }
        ovP[p * 128 + ch] = s;
    }
    __syncthreads();

    // ---- Phase 6: MLP layer 1 (128->256) + GN(4/64) + ReLU ----
    {
        const int o = tid;
        const float* wr = w_m0 + o * 128;
        float acc[2] = {0.f, 0.f};
        for (int c0 = 0; c0 < 128; c0 += 4) {
            float4 w4 = *(const float4*)(wr + c0);
            #pragma unroll
            for (int pp = 0; pp < 2; pp++) {
                float4 x4 = *(const float4*)(ovP + pp * 128 + c0);
                acc[pp] = fmaf(w4.x, x4.x, acc[pp]); acc[pp] = fmaf(w4.y, x4.y, acc[pp]);
                acc[pp] = fmaf(w4.z, x4.z, acc[pp]); acc[pp] = fmaf(w4.w, x4.w, acc[pp]);
            }
        }
        float bi = b_m0[o], gg = g_m0[o], bb = be_m0[o];
        #pragma unroll
        for (int pp = 0; pp < 2; pp++) {
            float v = acc[pp] + bi;
            float s = v, s2 = v * v;
            #pragma unroll
            for (int mk = 1; mk <= 32; mk <<= 1) { s += __shfl_xor(s, mk); s2 += __shfl_xor(s2, mk); }
            float mu = s * (1.f / 64.f);
            float rs = rsqrtf(s2 * (1.f / 64.f) - mu * mu + EPS);
            mmP[pp * 256 + o] = fmaxf(fmaf((v - mu) * rs, gg, bb), 0.f);
        }
    }
    __syncthreads();

    // ---- Phase 7: MLP layer 2 (256->128) + GN(4/32) + ReLU + out_norm GN(16/8) ----
    {
        const int o = tid & 127, pp = tid >> 7;
        const float* wr = w_m1 + o * 256;
        float acc = 0.f;
        for (int c0 = 0; c0 < 256; c0 += 4) {
            float4 w4 = *(const float4*)(wr + c0);
            float4 x4 = *(const float4*)(mmP + pp * 256 + c0);
            acc = fmaf(w4.x, x4.x, acc); acc = fmaf(w4.y, x4.y, acc);
            acc = fmaf(w4.z, x4.z, acc); acc = fmaf(w4.w, x4.w, acc);
        }
        float v = acc + b_m1[o];
        float s = v, s2 = v * v;
        #pragma unroll
        for (int mk = 1; mk <= 16; mk <<= 1) { s += __shfl_xor(s, mk); s2 += __shfl_xor(s2, mk); }
        float mu = s * (1.f / 32.f);
        float rs = rsqrtf(s2 * (1.f / 32.f) - mu * mu + EPS);
        float v2 = fmaxf(fmaf((v - mu) * rs, g_m1[o], be_m1[o]), 0.f);
        float t1 = v2, t2 = v2 * v2;
        #pragma unroll
        for (int mk = 1; mk <= 4; mk <<= 1) { t1 += __shfl_xor(t1, mk); t2 += __shfl_xor(t2, mk); }
        float mu2 = t1 * (1.f / 8.f);
        float rs2 = rsqrtf(t2 * (1.f / 8.f) - mu2 * mu2 + EPS);
        ysP[pp * 128 + o] = fmaf((v2 - mu2) * rs2, g_out[o], b_out[o]);
    }
    __syncthreads();

    // ---- Phase 8: store (float2 across the 2 pixels) ----
    if (tid < 128) {
        float2 y2;
        y2.x = ysP[0 * 128 + tid];
        y2.y = ysP[1 * 128 + tid];
        *(float2*)(out + ((size_t)(b * 128 + tid)) * HWp + pixbase) = y2;
    }
}

extern "C" void kernel_launch(void* const* d_in, const int* in_sizes, int n_in,
                              void* d_out, int out_size, void* d_ws, size_t ws_size,
                              hipStream_t stream) {
    const float* x        = (const float*)d_in[0];
    const int*   bpos     = (const int*)  d_in[1];
    const float* w_in0    = (const float*)d_in[2];
    const float* b_in0    = (const float*)d_in[3];
    const float* g_in0    = (const float*)d_in[4];
    const float* be_in0   = (const float*)d_in[5];
    const float* w_in1    = (const float*)d_in[6];
    const float* b_in1    = (const float*)d_in[7];
    const float* g_in1    = (const float*)d_in[8];
    const float* be_in1   = (const float*)d_in[9];
    const float* g_innorm = (const float*)d_in[10];
    const float* b_innorm = (const float*)d_in[11];
    const float* Qm       = (const float*)d_in[12];
    const float* w_k      = (const float*)d_in[13];
    const float* b_k      = (const float*)d_in[14];
    const float* w_m0     = (const float*)d_in[15];
    const float* b_m0     = (const float*)d_in[16];
    const float* g_m0     = (const float*)d_in[17];
    const float* be_m0    = (const float*)d_in[18];
    const float* w_m1     = (const float*)d_in[19];
    const float* b_m1     = (const float*)d_in[20];
    const float* g_m1     = (const float*)d_in[21];
    const float* be_m1    = (const float*)d_in[22];
    const float* g_out    = (const float*)d_in[23];
    const float* b_out    = (const float*)d_in[24];

    // ws layout (bytes): w1h@0, w1l@65536, w2h@131072, w2l@196608 (fp16, 32768 each)
    //                    qkBh@262144 (2048 fp16), qkBl@266240, qb2@270336 (16 f32)
    _Float16* w1h  = (_Float16*)d_ws;
    _Float16* w1l  = w1h + 32768;
    _Float16* w2h  = w1l + 32768;
    _Float16* w2l  = w2h + 32768;
    _Float16* qkBh = (_Float16*)((char*)d_ws + 262144);
    _Float16* qkBl = qkBh + 2048;
    float*    qb2G = (float*)((char*)d_ws + 270336);

    hipLaunchKernelGGL(ltae_prep, dim3(265), dim3(256), 0, stream,
                       w_in0, w_in1, Qm, w_k, b_k, w1h, w1l, w2h, w2l, qkBh, qkBl, qb2G);

    hipLaunchKernelGGL(ltae_main, dim3(4608), dim3(256), 0, stream,
                       x, bpos,
                       b_in0, g_in0, be_in0,
                       b_in1, g_in1, be_in1,
                       g_innorm, b_innorm,
                       w_m0, b_m0, g_m0, be_m0,
                       w_m1, b_m1, g_m1, be_m1,
                       g_out, b_out,
                       w1h, w1l, w2h, w2l, qkBh, qkBl, qb2G,
                       (float*)d_out);
}